// Round 13
// baseline (66.704 us; speedup 1.0000x reference)
//
#include <hip/hip_runtime.h>
#include <math.h>

#define NB 128
#define NR 36
#define NT 128
#define ND 1024
#define CST 260     // cap LDS row stride (f32): 1040 B (2-way banks on frag reads)

typedef float    f32x4 __attribute__((ext_vector_type(4)));
typedef _Float16 f16x8 __attribute__((ext_vector_type(8)));

__device__ __forceinline__ f16x8 cvt8(const float4 a, const float4 b) {
    f16x8 h;
    h[0] = (_Float16)a.x; h[1] = (_Float16)a.y; h[2] = (_Float16)a.z; h[3] = (_Float16)a.w;
    h[4] = (_Float16)b.x; h[5] = (_Float16)b.y; h[6] = (_Float16)b.z; h[7] = (_Float16)b.w;
    return h;
}
__device__ __forceinline__ f16x8 cvt8v(const f32x4 a, const f32x4 b) {
    f16x8 h;
    h[0] = (_Float16)a[0]; h[1] = (_Float16)a[1]; h[2] = (_Float16)a[2]; h[3] = (_Float16)a[3];
    h[4] = (_Float16)b[0]; h[5] = (_Float16)b[1]; h[6] = (_Float16)b[2]; h[7] = (_Float16)b[3];
    return h;
}
__device__ __forceinline__ float sq8(const float4 a, const float4 b, float s) {
    s = fmaf(a.x,a.x, fmaf(a.y,a.y, fmaf(a.z,a.z, fmaf(a.w,a.w, s))));
    return fmaf(b.x,b.x, fmaf(b.y,b.y, fmaf(b.z,b.z, fmaf(b.w,b.w, s))));
}
__device__ __forceinline__ float sq8v(const f32x4 a, const f32x4 b, float s) {
    s = fmaf(a[0],a[0], fmaf(a[1],a[1], fmaf(a[2],a[2], fmaf(a[3],a[3], s))));
    return fmaf(b[0],b[0], fmaf(b[1],b[1], fmaf(b[2],b[2], fmaf(b[3],b[3], s))));
}
// async global->LDS DMA: 16 B/lane; dest = uniform base + lane*16; source per-lane
__device__ __forceinline__ void gload_lds16(const void* g, float* l) {
    __builtin_amdgcn_global_load_lds(
        (const __attribute__((address_space(1))) void*)g,
        (__attribute__((address_space(3))) void*)l, 16, 0, 0);
}

// ======== Fused: scores (MFMA) + norms + softmax + pool (MFMA), one block = (b, 16 tokens) ========
__global__ __launch_bounds__(256, 2)
void scan_fused(const float* __restrict__ img, const float* __restrict__ cap,
                float* __restrict__ out) {
    __shared__ __align__(16) float capt[4][16][CST];   // 66560 B: per-wave cap K-window
    __shared__ float sc_s[16][49];                     //  3136 B (cols 36..48 garbage)
    __shared__ float ni_s[NR];                         //  img sumsq
    __shared__ float nc_s[16];                         //  cap sumsq
    __shared__ __align__(16) _Float16 w_s[16][72];     //  2304 B (pad 72: 2-way banks)

    const int tid  = threadIdx.x;
    const int phys = blockIdx.x;
    // XCD swizzle (bijective, 1024 = 8*128): all 8 token-groups of b on one XCD
    const int lb = (phys & 7) * 128 + (phys >> 3);
    const int b  = lb >> 3;
    const int t0 = (lb & 7) * 16;

    const float* imgB = img + (size_t)b * NR * ND;
    const float* capB = cap + ((size_t)b * NT + t0) * ND;
    float*       outB = out + ((size_t)(b * NT + t0)) * ND;

    const int wv = tid >> 6, lane = tid & 63, ln = lane & 15, hi = lane >> 4;
    const int kq = wv, kb = kq * 256;    // wave owns K-quarter

    // ---- zero reduction targets ----
    for (int i = tid; i < 16 * 49; i += 256) ((float*)sc_s)[i] = 0.f;
    if (tid < NR) ni_s[tid] = 0.f;
    if (tid < 16) nc_s[tid] = 0.f;

    // ---- A-phase DMA: 16 coalesced 1 KB rows of cap into this wave's LDS quadrant ----
    #pragma unroll
    for (int r = 0; r < 16; ++r) {
        const char* src = (const char*)(capB + (size_t)r * ND + kb) + lane * 16;
        gload_lds16(src, &capt[kq][r][0]);
    }
    __syncthreads();   // drains each wave's DMAs (vmcnt 0) + zero-init visible

    // ---- A-phase compute (r12-proven body): 8 MFMA steps over this K-quarter ----
    const float* cRow  = &capt[kq][ln][0] + hi * 8;
    const float* imgR0 = imgB + (size_t)ln * ND + kb + hi * 8;
    const float* imgR1 = imgB + (size_t)(16 + ln) * ND + kb + hi * 8;
    const float* imgR2 = imgB + (size_t)(32 + (ln < 4 ? ln : 3)) * ND + kb + hi * 8;

    f32x4 acc0 = {0.f,0.f,0.f,0.f}, acc1 = acc0, acc2 = acc0;
    float ncp = 0.f, ni0 = 0.f, ni1 = 0.f, ni2 = 0.f;

    #pragma unroll
    for (int s = 0; s < 8; ++s) {
        const f32x4 ca = *(const f32x4*)(cRow + s * 32);
        const f32x4 cb = *(const f32x4*)(cRow + s * 32 + 4);
        const float4 g00 = *(const float4*)(imgR0 + s * 32);
        const float4 g01 = *(const float4*)(imgR0 + s * 32 + 4);
        const float4 g10 = *(const float4*)(imgR1 + s * 32);
        const float4 g11 = *(const float4*)(imgR1 + s * 32 + 4);
        const float4 g20 = *(const float4*)(imgR2 + s * 32);
        const float4 g21 = *(const float4*)(imgR2 + s * 32 + 4);
        ncp = sq8v(ca, cb, ncp);
        ni0 = sq8(g00, g01, ni0);
        ni1 = sq8(g10, g11, ni1);
        ni2 = sq8(g20, g21, ni2);
        const f16x8 a = cvt8v(ca, cb);
        acc0 = __builtin_amdgcn_mfma_f32_16x16x32_f16(a, cvt8(g00, g01), acc0, 0, 0, 0);
        acc1 = __builtin_amdgcn_mfma_f32_16x16x32_f16(a, cvt8(g10, g11), acc1, 0, 0, 0);
        acc2 = __builtin_amdgcn_mfma_f32_16x16x32_f16(a, cvt8(g20, g21), acc2, 0, 0, 0);
    }

    // ---- combine K-quarters in LDS (C/D: col=ln -> region, row=hi*4+j -> token) ----
    #pragma unroll
    for (int j = 0; j < 4; ++j) {
        atomicAdd(&sc_s[hi * 4 + j][ln],      acc0[j]);
        atomicAdd(&sc_s[hi * 4 + j][16 + ln], acc1[j]);
        atomicAdd(&sc_s[hi * 4 + j][32 + ln], acc2[j]);   // ln>=4 garbage -> cols 36..47
    }
    // norms: reduce k within quarter (hi), all 4 kq waves combine -> full K
    {
        float s = ncp;  s += __shfl_xor(s, 16, 64); s += __shfl_xor(s, 32, 64);
        if (lane < 16) atomicAdd(&nc_s[ln], s);
        s = ni0;        s += __shfl_xor(s, 16, 64); s += __shfl_xor(s, 32, 64);
        if (lane < 16) atomicAdd(&ni_s[ln], s);
        s = ni1;        s += __shfl_xor(s, 16, 64); s += __shfl_xor(s, 32, 64);
        if (lane < 16) atomicAdd(&ni_s[16 + ln], s);
        s = ni2;        s += __shfl_xor(s, 16, 64); s += __shfl_xor(s, 32, 64);
        if (lane < 4)  atomicAdd(&ni_s[32 + ln], s);      // clamped lanes excluded
    }
    __syncthreads();

    // ---- softmax over regions, one thread per token; w -> LDS (cols 36..63 = 0) ----
    if (tid < 16) {
        const float nct = sqrtf(nc_s[tid]);
        float v[NR];
        float m = -1e30f;
        #pragma unroll
        for (int r = 0; r < NR; ++r) {
            const float d = fmaxf(sqrtf(ni_s[r]) * nct, 1e-8f);
            v[r] = sc_s[tid][r] / d;
            m = fmaxf(m, v[r]);
        }
        float sum = 0.f;
        #pragma unroll
        for (int r = 0; r < NR; ++r) { v[r] = __expf(v[r] - m); sum += v[r]; }
        const float inv = 1.f / sum;
        #pragma unroll
        for (int r = 0; r < 64; ++r)
            w_s[tid][r] = (r < NR) ? (_Float16)(v[r] * inv) : (_Float16)0.f;
    }
    __syncthreads();

    // ---- B-phase (pool_mfma-proven algebra): out[16][1024], wave owns 256 d ----
    f16x8 afr[2];
    #pragma unroll
    for (int kk = 0; kk < 2; ++kk)
        afr[kk] = *(const f16x8*)(&w_s[ln][kk * 32 + hi * 8]);   // A[m=token ln][k=region]

    f32x4 accb[16];
    #pragma unroll
    for (int nf = 0; nf < 16; ++nf) accb[nf] = (f32x4){0.f, 0.f, 0.f, 0.f};

    #pragma unroll
    for (int nf = 0; nf < 16; ++nf) {
        const int dcol = wv * 256 + nf * 16 + ln;
        #pragma unroll
        for (int kk = 0; kk < 2; ++kk) {
            f16x8 bfr;
            #pragma unroll
            for (int j = 0; j < 8; ++j) {
                int r = kk * 32 + hi * 8 + j;
                if (r >= NR) r = NR - 1;             // safe addr; killed by w==0
                bfr[j] = (_Float16)imgB[(size_t)r * ND + dcol];
            }
            accb[nf] = __builtin_amdgcn_mfma_f32_16x16x32_f16(afr[kk], bfr, accb[nf], 0, 0, 0);
        }
    }

    // store: D row = hi*4+j (token), col = wv*256 + nf*16 + ln (d)
    #pragma unroll
    for (int nf = 0; nf < 16; ++nf)
        #pragma unroll
        for (int j = 0; j < 4; ++j)
            outB[(size_t)(hi * 4 + j) * ND + wv * 256 + nf * 16 + ln] = accb[nf][j];
}

extern "C" void kernel_launch(void* const* d_in, const int* in_sizes, int n_in,
                              void* d_out, int out_size, void* d_ws, size_t ws_size,
                              hipStream_t stream) {
    const float* img = (const float*)d_in[0];   // [B, R, D]
    const float* cap = (const float*)d_in[1];   // [B, T, D]
    float* out = (float*)d_out;                 // [B, T, D]
    scan_fused<<<NB * 8, 256, 0, stream>>>(img, cap, out);
}

// Round 14
// 60.849 us; speedup vs baseline: 1.0962x; 1.0962x over previous
//
#include <hip/hip_runtime.h>
#include <math.h>

#define NB 128
#define NR 36
#define NT 128
#define ND 1024
#define WST 64      // w row stride in ws (f16), cols 36..63 = 0

typedef float    f32x4 __attribute__((ext_vector_type(4)));
typedef _Float16 f16x8 __attribute__((ext_vector_type(8)));

__device__ __forceinline__ f16x8 cvt8(const float4 a, const float4 b) {
    f16x8 h;
    h[0] = (_Float16)a.x; h[1] = (_Float16)a.y; h[2] = (_Float16)a.z; h[3] = (_Float16)a.w;
    h[4] = (_Float16)b.x; h[5] = (_Float16)b.y; h[6] = (_Float16)b.z; h[7] = (_Float16)b.w;
    return h;
}
__device__ __forceinline__ f16x8 cvt8v(const f32x4 a, const f32x4 b) {
    f16x8 h;
    h[0] = (_Float16)a[0]; h[1] = (_Float16)a[1]; h[2] = (_Float16)a[2]; h[3] = (_Float16)a[3];
    h[4] = (_Float16)b[0]; h[5] = (_Float16)b[1]; h[6] = (_Float16)b[2]; h[7] = (_Float16)b[3];
    return h;
}
__device__ __forceinline__ float sq8(const float4 a, const float4 b, float s) {
    s = fmaf(a.x,a.x, fmaf(a.y,a.y, fmaf(a.z,a.z, fmaf(a.w,a.w, s))));
    return fmaf(b.x,b.x, fmaf(b.y,b.y, fmaf(b.z,b.z, fmaf(b.w,b.w, s))));
}
__device__ __forceinline__ float sq8v(const f32x4 a, const f32x4 b, float s) {
    s = fmaf(a[0],a[0], fmaf(a[1],a[1], fmaf(a[2],a[2], fmaf(a[3],a[3], s))));
    return fmaf(b[0],b[0], fmaf(b[1],b[1], fmaf(b[2],b[2], fmaf(b[3],b[3], s))));
}
// async global->LDS DMA: 16 B/lane; dest = wave-uniform base (+ lane*16); source per-lane
__device__ __forceinline__ void gload_lds16(const void* g, float* l) {
    __builtin_amdgcn_global_load_lds(
        (const __attribute__((address_space(1))) void*)g,
        (__attribute__((address_space(3))) void*)l, 16, 0, 0);
}

// ============ Kernel A: cosine scores + softmax -> w (f16). Small-LDS / 8-blocks-per-CU ============
__global__ __launch_bounds__(256, 6)
void scores_softmax(const float* __restrict__ img, const float* __restrict__ cap,
                    _Float16* __restrict__ w_ws) {
    __shared__ __align__(16) float buf[2][16][128];   // 16384 B cap K-chunk (linear rows)
    __shared__ float sc_s[16][49];                    //  3136 B
    __shared__ float ni_s[NR];
    __shared__ float nc_s[16];

    const int tid  = threadIdx.x;
    const int phys = blockIdx.x;
    // XCD swizzle (bijective, 1024 = 8*128): all 8 token-groups of b on one XCD
    const int lb = (phys & 7) * 128 + (phys >> 3);
    const int b  = lb >> 3;
    const int t0 = (lb & 7) * 16;

    const float* imgB = img + (size_t)b * NR * ND;
    const float* capB = cap + ((size_t)b * NT + t0) * ND;

    const int wv = tid >> 6, lane = tid & 63, ln = lane & 15, hi = lane >> 4;
    const int kq = wv;   // wave's K-quarter within each 128-chunk (32 f32 = one MFMA)

    for (int i = tid; i < 16 * 49; i += 256) ((float*)sc_s)[i] = 0.f;
    if (tid < NR) ni_s[tid] = 0.f;
    if (tid < 16) nc_s[tid] = 0.f;

    // stage chunk c into buf[cb]: 8 x 1KB DMA (2 per wave), source XOR-swizzled per row
    const int srow = 4 * wv + ((lane >> 5) ? 1 : 0);  // base row parity within pair
    #define STAGE(c, cb)                                                            \
        _Pragma("unroll")                                                           \
        for (int p = 0; p < 2; ++p) {                                               \
            const int row = 4 * wv + 2 * p + (lane >> 5);                           \
            const char* src = (const char*)(capB + (size_t)row * ND + (c) * 128)    \
                              + (((lane & 31) * 16) ^ ((row & 7) << 4));            \
            gload_lds16(src, &buf[cb][4 * wv + 2 * p][0]);                          \
        }

    STAGE(0, 0)
    __syncthreads();   // chunk 0 ready (vmcnt0 drain) + zero-init visible

    const int xa = (ln & 7) << 4;                     // read-side XOR for cap row ln
    const float* imgR0 = imgB + (size_t)ln * ND;
    const float* imgR1 = imgB + (size_t)(16 + ln) * ND;
    const float* imgR2 = imgB + (size_t)(32 + (ln < 4 ? ln : 3)) * ND;

    f32x4 acc0 = {0.f,0.f,0.f,0.f}, acc1 = acc0, acc2 = acc0;
    float ncp = 0.f, ni0 = 0.f, ni1 = 0.f, ni2 = 0.f;

    int cur = 0;
    for (int c = 0; c < 8; ++c) {
        if (c < 7) STAGE(c + 1, cur ^ 1)
        // ---- compute chunk c: one MFMA step per wave (K cols kq*32..+32) ----
        const char* cbase = (const char*)&buf[cur][0][0] + ln * 512;
        const int off = kq * 128 + hi * 32;
        const f32x4 ca = *(const f32x4*)(cbase + ( off       ^ xa));
        const f32x4 cb = *(const f32x4*)(cbase + ((off + 16) ^ xa));
        const int co = c * 128 + kq * 32 + hi * 8;
        const float4 g00 = *(const float4*)(imgR0 + co);
        const float4 g01 = *(const float4*)(imgR0 + co + 4);
        const float4 g10 = *(const float4*)(imgR1 + co);
        const float4 g11 = *(const float4*)(imgR1 + co + 4);
        const float4 g20 = *(const float4*)(imgR2 + co);
        const float4 g21 = *(const float4*)(imgR2 + co + 4);
        ncp = sq8v(ca, cb, ncp);
        ni0 = sq8(g00, g01, ni0);
        ni1 = sq8(g10, g11, ni1);
        ni2 = sq8(g20, g21, ni2);
        const f16x8 a = cvt8v(ca, cb);
        acc0 = __builtin_amdgcn_mfma_f32_16x16x32_f16(a, cvt8(g00, g01), acc0, 0, 0, 0);
        acc1 = __builtin_amdgcn_mfma_f32_16x16x32_f16(a, cvt8(g10, g11), acc1, 0, 0, 0);
        acc2 = __builtin_amdgcn_mfma_f32_16x16x32_f16(a, cvt8(g20, g21), acc2, 0, 0, 0);
        __syncthreads();   // c+1 DMAs complete; buf[cur] reads done before overwrite
        cur ^= 1;
    }

    // ---- combine K-quarters (C/D: col=ln -> region, row=hi*4+j -> token; proven) ----
    #pragma unroll
    for (int j = 0; j < 4; ++j) {
        atomicAdd(&sc_s[hi * 4 + j][ln],      acc0[j]);
        atomicAdd(&sc_s[hi * 4 + j][16 + ln], acc1[j]);
        atomicAdd(&sc_s[hi * 4 + j][32 + ln], acc2[j]);   // ln>=4 garbage -> cols 36..47
    }
    {
        float s = ncp;  s += __shfl_xor(s, 16, 64); s += __shfl_xor(s, 32, 64);
        if (lane < 16) atomicAdd(&nc_s[ln], s);
        s = ni0;        s += __shfl_xor(s, 16, 64); s += __shfl_xor(s, 32, 64);
        if (lane < 16) atomicAdd(&ni_s[ln], s);
        s = ni1;        s += __shfl_xor(s, 16, 64); s += __shfl_xor(s, 32, 64);
        if (lane < 16) atomicAdd(&ni_s[16 + ln], s);
        s = ni2;        s += __shfl_xor(s, 16, 64); s += __shfl_xor(s, 32, 64);
        if (lane < 4)  atomicAdd(&ni_s[32 + ln], s);      // clamped lanes excluded
    }
    __syncthreads();

    // ---- softmax over regions, one thread per token; write w (f16, cols 36..63=0) ----
    if (tid < 16) {
        const float nct = sqrtf(nc_s[tid]);
        float v[NR];
        float m = -1e30f;
        #pragma unroll
        for (int r = 0; r < NR; ++r) {
            const float d = fmaxf(sqrtf(ni_s[r]) * nct, 1e-8f);
            v[r] = sc_s[tid][r] / d;
            m = fmaxf(m, v[r]);
        }
        float sum = 0.f;
        #pragma unroll
        for (int r = 0; r < NR; ++r) { v[r] = __expf(v[r] - m); sum += v[r]; }
        const float inv = 1.f / sum;
        _Float16* wO = w_ws + (size_t)(b * NT + t0 + tid) * WST;
        #pragma unroll
        for (int q = 0; q < 8; ++q) {
            f16x8 h;
            #pragma unroll
            for (int j = 0; j < 8; ++j) {
                const int r = q * 8 + j;
                h[j] = (r < NR) ? (_Float16)(v[r] * inv) : (_Float16)0.f;
            }
            *(f16x8*)(wO + q * 8) = h;
        }
    }
}

// ============ Kernel B: out[t][d] = sum_r w[t][r] * img[r][d] via MFMA (proven) ============
__global__ __launch_bounds__(256, 4)
void pool_mfma(const float* __restrict__ img, const _Float16* __restrict__ w_ws,
               float* __restrict__ out) {
    const int tid  = threadIdx.x;
    const int phys = blockIdx.x;
    const int lb = (phys & 7) * 256 + (phys >> 3);   // same XCD->batch mapping as kernel A
    const int b  = lb >> 4;
    const int tq = (lb >> 2) & 3;
    const int dq = lb & 3;
    const int t0 = tq * 32;

    const int wv = tid >> 6, lane = tid & 63, ln = lane & 15, hi = lane >> 4;
    const int dw = dq * 256 + wv * 64;

    const float*    imgB = img  + (size_t)b * NR * ND;
    const _Float16* wB   = w_ws + (size_t)(b * NT + t0) * WST;
    float*          outB = out  + ((size_t)(b * NT + t0)) * ND;

    f16x8 afr[2][2];
    #pragma unroll
    for (int mfr = 0; mfr < 2; ++mfr)
        #pragma unroll
        for (int kk = 0; kk < 2; ++kk)
            afr[mfr][kk] = *(const f16x8*)(wB + (mfr * 16 + ln) * WST + kk * 32 + hi * 8);

    f32x4 acc[2][4];
    #pragma unroll
    for (int mfr = 0; mfr < 2; ++mfr)
        #pragma unroll
        for (int nf = 0; nf < 4; ++nf)
            acc[mfr][nf] = (f32x4){0.f, 0.f, 0.f, 0.f};

    #pragma unroll
    for (int nf = 0; nf < 4; ++nf) {
        const int dcol = dw + nf * 16 + ln;
        #pragma unroll
        for (int kk = 0; kk < 2; ++kk) {
            f16x8 bfr;
            #pragma unroll
            for (int j = 0; j < 8; ++j) {
                int r = kk * 32 + hi * 8 + j;
                if (r >= NR) r = NR - 1;             // safe addr; killed by w==0
                bfr[j] = (_Float16)imgB[r * ND + dcol];
            }
            #pragma unroll
            for (int mfr = 0; mfr < 2; ++mfr)
                acc[mfr][nf] = __builtin_amdgcn_mfma_f32_16x16x32_f16(afr[mfr][kk], bfr, acc[mfr][nf], 0, 0, 0);
        }
    }

    #pragma unroll
    for (int mfr = 0; mfr < 2; ++mfr)
        #pragma unroll
        for (int nf = 0; nf < 4; ++nf)
            #pragma unroll
            for (int j = 0; j < 4; ++j)
                outB[(size_t)(mfr * 16 + hi * 4 + j) * ND + dw + nf * 16 + ln] = acc[mfr][nf][j];
}

extern "C" void kernel_launch(void* const* d_in, const int* in_sizes, int n_in,
                              void* d_out, int out_size, void* d_ws, size_t ws_size,
                              hipStream_t stream) {
    const float* img = (const float*)d_in[0];   // [B, R, D]
    const float* cap = (const float*)d_in[1];   // [B, T, D]
    float* out = (float*)d_out;                 // [B, T, D]
    _Float16* w_ws = (_Float16*)d_ws;           // [B, T, 64] f16 = 2.0 MB

    scores_softmax<<<NB * 8, 256, 0, stream>>>(img, cap, w_ws);
    pool_mfma<<<NB * 16, 256, 0, stream>>>(img, w_ws, out);
}